// Round 5
// baseline (1349.326 us; speedup 1.0000x reference)
//
#include <hip/hip_runtime.h>

namespace {

constexpr int THREADS = 64;

struct c32 { float r, i; };

__device__ __forceinline__ c32 cmul(c32 a, c32 b) {
    return { fmaf(a.r, b.r, -(a.i * b.i)), fmaf(a.r, b.i, a.i * b.r) };
}

__device__ __forceinline__ float rlf(float v, int lane) {
    return __int_as_float(__builtin_amdgcn_readlane(__float_as_int(v), lane));
}

struct G8 { float r00,i00,r01,i01,r10,i10,r11,i11; };

__device__ __forceinline__ G8 rgate(const G8& o, int lane) {
    G8 g;
    g.r00 = rlf(o.r00, lane); g.i00 = rlf(o.i00, lane);
    g.r01 = rlf(o.r01, lane); g.i01 = rlf(o.i01, lane);
    g.r10 = rlf(o.r10, lane); g.i10 = rlf(o.i10, lane);
    g.r11 = rlf(o.r11, lane); g.i11 = rlf(o.i11, lane);
    return g;
}

// scalar-coefficient complex butterfly: (x,y) <- (g00 x + g01 y, g10 x + g11 y)
__device__ __forceinline__ void bfs(c32& x, c32& y, const G8& g) {
    const c32 a = x, b = y;
    x.r = fmaf(g.r00, a.r, fmaf(-g.i00, a.i, fmaf(g.r01, b.r, -(g.i01 * b.i))));
    x.i = fmaf(g.r00, a.i, fmaf( g.i00, a.r, fmaf(g.r01, b.i,   g.i01 * b.r)));
    y.r = fmaf(g.r10, a.r, fmaf(-g.i10, a.i, fmaf(g.r11, b.r, -(g.i11 * b.i))));
    y.i = fmaf(g.r10, a.i, fmaf( g.i10, a.r, fmaf(g.r11, b.i,   g.i11 * b.r)));
}

// apply gate to register bit BP of the 64-amplitude register file
template<int BP>
__device__ __forceinline__ void ag(c32 v[64], const G8& g) {
    #pragma unroll
    for (int mi = 0; mi < 32; ++mi) {
        const int i0 = ((mi >> BP) << (BP + 1)) | (mi & ((1 << BP) - 1));
        bfs(v[i0], v[i0 | (1 << BP)], g);
    }
}

// 6-bit suffix-xor (inverse of gray g(x)=x^(x>>1))
__host__ __device__ constexpr int g2b6c(int s) { s ^= s >> 1; s ^= s >> 2; s ^= s >> 4; return s & 63; }

// ---- transpose A->B (plain). A: thread=t[5:0], reg=t[11:6] -> B: thread=t[11:6], reg=t[5:0]
// chunk c = {t : t11 ^ t5 = c}; e = t[4:0]*64 + (t[11:6] ^ t[4:0]); 16KB buffer reused.
__device__ __forceinline__ void tA2B(c32 v[64], char* L, int tid) {
    const int t5 = tid & 31, h = tid >> 5;
    const unsigned BW = (unsigned)(t5 * 512 + t5 * 8);   // byte base (write side)
    const unsigned BR = (unsigned)(tid * 8);             // xor base (read side)
    #pragma unroll
    for (int c = 0; c < 2; ++c) {
        const int hb = h ^ c;   // half selector, uniform per thread
        if (hb == 0) {
            #pragma unroll
            for (int r = 0; r < 32; ++r)
                *(float2*)(L + (BW ^ (unsigned)(r * 8))) = make_float2(v[r].r, v[r].i);
        } else {
            #pragma unroll
            for (int r = 32; r < 64; ++r)
                *(float2*)(L + (BW ^ (unsigned)(r * 8))) = make_float2(v[r].r, v[r].i);
        }
        __syncthreads();
        if (hb == 0) {
            #pragma unroll
            for (int m = 0; m < 32; ++m) {
                const float2 t = *(const float2*)(L + ((unsigned)((m & 31) * 512 + (m & 31) * 8) ^ BR));
                v[m] = { t.x, t.y };
            }
        } else {
            #pragma unroll
            for (int m = 32; m < 64; ++m) {
                const float2 t = *(const float2*)(L + ((unsigned)((m & 31) * 512 + (m & 31) * 8) ^ BR));
                v[m] = { t.x, t.y };
            }
        }
        __syncthreads();
    }
}

// ---- transpose B->A with CNOT-ladder fold. Source B: s[11:6]=tid, s[5:0]=m.
// Dest u = g2b12(s): u[11:6]=g2b6(tid), u[5:0]=g2b6(m)^63P, P=popc(tid)&1.
// chunk bit chi = u10^u5^u4 => writer slots {m: m4=bb}, reader regs {r: r4=bb},
// bb = (tid5^tid4)^c : identical per-thread index sets (safe in-place).
// e = u[4:0]*64 + (((k ^ u[4:0]) & 31) | (u5<<5)), k = (u[9:6]) | (u11<<4).
__device__ __forceinline__ void tB2Ag(c32 v[64], char* L, int tid) {
    const int t5 = tid & 31;
    const int U  = g2b6c(tid);              // runtime ok: same formula
    const int P  = __popc(tid) & 1;
    const int P31 = P ? 31 : 0;
    const int kthr = (U & 15) | (((tid >> 5) & 1) << 4);
    const unsigned TB2  = (unsigned)((P31 * 512) ^ ((kthr ^ P31) * 8) ^ (P * 256));
    const unsigned BASE3 = (unsigned)(t5 * 512 + t5 * 8 + ((tid >> 5) & 1) * 256);
    const int bsel = ((tid >> 5) ^ (tid >> 4)) & 1;
    #pragma unroll
    for (int c = 0; c < 2; ++c) {
        const int bb = bsel ^ c;
        if (bb == 0) {
            #pragma unroll
            for (int m = 0; m < 64; ++m) {
                if constexpr (true) {}
                if (((m >> 4) & 1) == 0) {
                    const unsigned CW = (unsigned)(((g2b6c(m) & 31) * 512) | ((g2b6c(m) & 31) * 8) | (((m >> 5) & 1) * 256));
                    *(float2*)(L + (CW ^ TB2)) = make_float2(v[m].r, v[m].i);
                }
            }
        } else {
            #pragma unroll
            for (int m = 0; m < 64; ++m) {
                if (((m >> 4) & 1) == 1) {
                    const unsigned CW = (unsigned)(((g2b6c(m) & 31) * 512) | ((g2b6c(m) & 31) * 8) | (((m >> 5) & 1) * 256));
                    *(float2*)(L + (CW ^ TB2)) = make_float2(v[m].r, v[m].i);
                }
            }
        }
        __syncthreads();
        if (bb == 0) {
            #pragma unroll
            for (int r = 0; r < 64; ++r) {
                if (((r >> 4) & 1) == 0) {
                    const int k = (r & 15) | ((r >> 5) << 4);
                    const float2 t = *(const float2*)(L + (BASE3 ^ (unsigned)(k * 8)));
                    v[r] = { t.x, t.y };
                }
            }
        } else {
            #pragma unroll
            for (int r = 0; r < 64; ++r) {
                if (((r >> 4) & 1) == 1) {
                    const int k = (r & 15) | ((r >> 5) << 4);
                    const float2 t = *(const float2*)(L + (BASE3 ^ (unsigned)(k * 8)));
                    v[r] = { t.x, t.y };
                }
            }
        }
        __syncthreads();
    }
}

__global__ __launch_bounds__(THREADS, 2)
void qcirc_kernel(const float* __restrict__ x, const float* __restrict__ thetas,
                  float* __restrict__ out) {
    __shared__ float2 lds[2048];   // 16 KB transpose chunk buffer
    char* L = (char*)lds;

    const int tid = threadIdx.x;
    const int b = blockIdx.x;

    // ---- per-lane fused gate build: lane g holds V(l=g/12, q=g%12) = RX RZ RX RZfm RYfm
    const float xv = x[b];
    const float x1 = asinf(xv);
    const float x2 = acosf(xv * xv);
    const float cy = cosf(0.5f * x1), sy = sinf(0.5f * x1);
    const float cz = cosf(0.5f * x2), sz = sinf(0.5f * x2);
    const c32 M00 = {  cz * cy, -sz * cy };
    const c32 M01 = { -cz * sy,  sz * sy };
    const c32 M10 = {  cz * sy,  sz * sy };
    const c32 M11 = {  cz * cy,  sz * cy };

    G8 own;
    {
        const int gl = tid < 48 ? tid : 0;
        const float* th = thetas + gl * 3;
        const float h0 = 0.5f * th[0], h1 = 0.5f * th[1], h2 = 0.5f * th[2];
        const float c0 = cosf(h0), s0 = sinf(h0);
        const float c1 = cosf(h1), s1 = sinf(h1);
        const float c2 = cosf(h2), s2 = sinf(h2);
        const c32 z0 = { c1, -s1 }, z1 = { c1, s1 };
        const c32 X00 = { c0, 0.f }, X01 = { 0.f, -s0 };
        const c32 A00 = cmul(z0, X00), A01 = cmul(z0, X01);
        const c32 A10 = cmul(z1, X01), A11 = cmul(z1, X00);
        const c32 Y00 = { c2, 0.f }, Y01 = { 0.f, -s2 };
        const c32 U00 = { Y00.r*A00.r - Y00.i*A00.i + Y01.r*A10.r - Y01.i*A10.i,
                          Y00.r*A00.i + Y00.i*A00.r + Y01.r*A10.i + Y01.i*A10.r };
        const c32 U01 = { Y00.r*A01.r - Y00.i*A01.i + Y01.r*A11.r - Y01.i*A11.i,
                          Y00.r*A01.i + Y00.i*A01.r + Y01.r*A11.i + Y01.i*A11.r };
        const c32 U10 = { Y01.r*A00.r - Y01.i*A00.i + Y00.r*A10.r - Y00.i*A10.i,
                          Y01.r*A00.i + Y01.i*A00.r + Y00.r*A10.i + Y00.i*A10.r };
        const c32 U11 = { Y01.r*A01.r - Y01.i*A01.i + Y00.r*A11.r - Y00.i*A11.i,
                          Y01.r*A01.i + Y01.i*A01.r + Y00.r*A11.i + Y00.i*A11.r };
        own.r00 = U00.r*M00.r - U00.i*M00.i + U01.r*M10.r - U01.i*M10.i;
        own.i00 = U00.r*M00.i + U00.i*M00.r + U01.r*M10.i + U01.i*M10.r;
        own.r01 = U00.r*M01.r - U00.i*M01.i + U01.r*M11.r - U01.i*M11.i;
        own.i01 = U00.r*M01.i + U00.i*M01.r + U01.r*M11.i + U01.i*M11.r;
        own.r10 = U10.r*M00.r - U10.i*M00.i + U11.r*M10.r - U11.i*M10.i;
        own.i10 = U10.r*M00.i + U10.i*M00.r + U11.r*M10.i + U11.i*M10.r;
        own.r11 = U10.r*M01.r - U10.i*M01.i + U11.r*M11.r - U11.i*M11.i;
        own.i11 = U10.r*M01.i + U10.i*M01.r + U11.r*M11.i + U11.i*M11.r;
    }

    // ---- layer 0 with CNOT-ladder #1 folded: v[r] = amp at new-index u=(r,tid),
    // value = prod_q E_q[bit of s], s = gamma(u). s[11:6]=gray6(r), s[5:0]=gray6(tid)^(r0<<5).
    c32 v[64];
    v[0] = { 1.f, 0.f };
    #pragma unroll
    for (int k = 0; k < 6; ++k) {             // bit k of a=s[11:6], qubit 5-k
        const int q = 5 - k;
        const c32 e0 = { rlf(own.r00, q), rlf(own.i00, q) };
        const c32 e1 = { rlf(own.r10, q), rlf(own.i10, q) };
        #pragma unroll
        for (int a2 = 0; a2 < (1 << k); ++a2) {
            const int src = g2b6c(a2);
            const int dst = g2b6c(a2 | (1 << k));
            v[dst] = cmul(v[src], e1);
            v[src] = cmul(v[src], e0);
        }
    }
    {
        const int gb = (tid ^ (tid >> 1)) & 63;   // gray6(tid)
        c32 Tc = { 1.f, 0.f };
        #pragma unroll
        for (int q = 11; q >= 7; --q) {
            const c32 e0 = { rlf(own.r00, q), rlf(own.i00, q) };
            const c32 e1 = { rlf(own.r10, q), rlf(own.i10, q) };
            const bool bit = (gb >> (11 - q)) & 1;
            const c32 e = { bit ? e1.r : e0.r, bit ? e1.i : e0.i };
            Tc = cmul(Tc, e);
        }
        const c32 e0 = { rlf(own.r00, 6), rlf(own.i00, 6) };
        const c32 e1 = { rlf(own.r10, 6), rlf(own.i10, 6) };
        const bool b5 = (gb >> 5) & 1;
        const c32 s0 = { b5 ? e1.r : e0.r, b5 ? e1.i : e0.i };
        const c32 s1 = { b5 ? e0.r : e1.r, b5 ? e0.i : e1.i };
        const c32 T0 = cmul(Tc, s0);
        const c32 T1 = cmul(Tc, s1);
        #pragma unroll
        for (int r = 0; r < 64; ++r)
            v[r] = cmul(v[r], (r & 1) ? T1 : T0);
    }

    // ---- 6 phases: layers 1..3 x {A: qubits 0-5, B: qubits 6-11}
    #pragma unroll 1
    for (int p = 0; p < 6; ++p) {
        const int l = 1 + (p >> 1);
        const int lane0 = l * 12 + (p & 1) * 6;
        { const G8 g = rgate(own, lane0 + 0); ag<5>(v, g); }
        { const G8 g = rgate(own, lane0 + 1); ag<4>(v, g); }
        { const G8 g = rgate(own, lane0 + 2); ag<3>(v, g); }
        { const G8 g = rgate(own, lane0 + 3); ag<2>(v, g); }
        { const G8 g = rgate(own, lane0 + 4); ag<1>(v, g); }
        { const G8 g = rgate(own, lane0 + 5); ag<0>(v, g); }
        if (p == 5) break;
        if ((p & 1) == 0) tA2B(v, L, tid);
        else              tB2Ag(v, L, tid);
    }

    // ---- readout (B-orientation, ladder #4 folded): weight = parity(s & 0x555)
    float acc = 0.f;
    #pragma unroll
    for (int m = 0; m < 64; ++m) {
        const float m2 = fmaf(v[m].r, v[m].r, v[m].i * v[m].i);
        acc += (__popc(m & 0x15) & 1) ? -m2 : m2;
    }
    if (__popc(tid & 0x15) & 1) acc = -acc;
    #pragma unroll
    for (int off = 32; off > 0; off >>= 1) acc += __shfl_down(acc, off, 64);
    if (tid == 0) out[b] = acc;
}

} // namespace

extern "C" void kernel_launch(void* const* d_in, const int* in_sizes, int n_in,
                              void* d_out, int out_size, void* d_ws, size_t ws_size,
                              hipStream_t stream) {
    const float* x      = (const float*)d_in[0];
    const float* thetas = (const float*)d_in[1];
    float* out          = (float*)d_out;
    const int batch = in_sizes[0];
    qcirc_kernel<<<batch, THREADS, 0, stream>>>(x, thetas, out);
}

// Round 6
// 90.584 us; speedup vs baseline: 14.8959x; 14.8959x over previous
//
#include <hip/hip_runtime.h>

namespace {

constexpr int NQ = 12;
constexpr int DIM = 1 << NQ;   // 4096
constexpr int THREADS = 256;

struct c32 { float r, i; };

__device__ __forceinline__ c32 cmul(c32 a, c32 b) {
    return { fmaf(a.r, b.r, -(a.i * b.i)), fmaf(a.r, b.i, a.i * b.r) };
}

// real-coefficient RY butterfly: (x,y) <- (cb*x - sb*y, sb*x + cb*y), 8 ops/pair
__device__ __forceinline__ void bfy(c32& x, c32& y, float cb, float sb) {
    const c32 a = x, b = y;
    x.r = fmaf(cb, a.r, -(sb * b.r));
    x.i = fmaf(cb, a.i, -(sb * b.i));
    y.r = fmaf(sb, a.r, cb * b.r);
    y.i = fmaf(sb, a.i, cb * b.i);
}

template<int BP>
__device__ __forceinline__ void applyRY(c32 v[16], float cb, float sb) {
    #pragma unroll
    for (int mi = 0; mi < 8; ++mi) {
        const int i0 = ((mi >> BP) << (BP + 1)) | (mi & ((1 << BP) - 1));
        bfy(v[i0], v[i0 | (1 << BP)], cb, sb);
    }
}

// ---- XOR-linear address algebra (identical to the passing R2 kernel) ----
__host__ __device__ constexpr int G(int t, int k) {
    for (int i = 0; i < k; ++i) t = (t ^ (t >> 1)) & 0xFFF;
    return t;
}
__host__ __device__ constexpr int Cm(int t) {
    int lo = 0;
    if (t & 0x010) lo ^= 0x2;
    if (t & 0x020) lo ^= 0x4;
    if (t & 0x040) lo ^= 0x8;
    if (t & 0x080) lo ^= 0x6;
    if (t & 0x100) lo ^= 0xA;
    if (t & 0x200) lo ^= 0xC;
    return t ^ lo;
}
__host__ __device__ constexpr int maskE_calc() {
    int m = 0;
    for (int i = 0; i < 12; ++i) {
        int v = G(Cm(1 << i), 12), p = 0;
        while (v) { p ^= (v & 1); v >>= 1; }
        if (p) m |= (1 << i);
    }
    return m;
}
constexpr int MASKE = maskE_calc();

// per-thread diag product tree for layer 0:
// T[j] = C * prod_{m=3..0} pf[m][j_m] * (qv[m] if (sigma ^ sfx_m(j)) else 1)
__device__ __forceinline__ void diagTree(c32 T[16], c32 C,
                                         const c32 pf0[4], const c32 pf1[4],
                                         const c32 qv[4], int sigma) {
    const c32 one = { 1.f, 0.f };
    T[0] = C;
    #pragma unroll
    for (int m = 3; m >= 0; --m) {
        const c32 qs0 = sigma ? qv[m] : one;   // sfx_m = 0
        const c32 qs1 = sigma ? one : qv[m];   // sfx_m = 1
        const c32 g00 = cmul(pf0[m], qs0);
        const c32 g01 = cmul(pf0[m], qs1);
        const c32 g10 = cmul(pf1[m], qs0);
        const c32 g11 = cmul(pf1[m], qs1);
        #pragma unroll
        for (int e = (1 << (3 - m)) - 1; e >= 0; --e) {
            const int j0 = e << (m + 1);
            const int sfxhi = __popc(e) & 1;                  // compile-time
            const c32 ga = sfxhi ? g01 : g00;                 // j_m=0: sfx=sfxhi
            const c32 gb = sfxhi ? g10 : g11;                 // j_m=1: sfx=sfxhi^1
            T[j0 | (1 << m)] = cmul(T[j0], gb);
            T[j0]            = cmul(T[j0], ga);
        }
    }
}

__global__ __launch_bounds__(THREADS)
void qcirc_kernel(const float* __restrict__ x, const float* __restrict__ thetas,
                  float* __restrict__ out) {
    __shared__ alignas(16) float2 amp[DIM];   // 32 KB state, layout Cm(G(t,l))
    __shared__ float4 Vs[4 * NQ * 2];         // per gate: (cb,sb,p0) , (p1,q1)
    __shared__ float2 TbS[2][2][16];          // boundary reg-part tables [K-1][sigma][j]
    __shared__ float2 CHiS[2][16];            // boundary thread-part, high nibble
    __shared__ float2 CLoS[2][2][16];         // boundary thread-part, low nibble [K-1][sigma_h][lo]
    __shared__ float red[4];
    float4* a4 = reinterpret_cast<float4*>(amp);

    const int tid = threadIdx.x;
    const int b = blockIdx.x;

    // ---- fused gate build + ZYZ-style decomposition: V = P * Ry(b) * Q, Q=diag(1,q1) ----
    const float xv = x[b];
    const float x1 = asinf(xv);
    const float x2 = acosf(xv * xv);
    const float cy = cosf(0.5f * x1), sy = sinf(0.5f * x1);
    const float cz = cosf(0.5f * x2), sz = sinf(0.5f * x2);
    const c32 M00 = {  cz * cy, -sz * cy };
    const c32 M01 = { -cz * sy,  sz * sy };
    const c32 M10 = {  cz * sy,  sz * sy };
    const c32 M11 = {  cz * cy,  sz * cy };

    if (tid < 4 * NQ) {
        const float* th = thetas + tid * 3;
        const float h0 = 0.5f * th[0], h1 = 0.5f * th[1], h2 = 0.5f * th[2];
        const float c0 = cosf(h0), s0 = sinf(h0);
        const float c1 = cosf(h1), s1 = sinf(h1);
        const float c2 = cosf(h2), s2 = sinf(h2);
        const c32 z0 = { c1, -s1 }, z1 = { c1, s1 };
        const c32 X00 = { c0, 0.f }, X01 = { 0.f, -s0 };
        const c32 A00 = cmul(z0, X00), A01 = cmul(z0, X01);
        const c32 A10 = cmul(z1, X01), A11 = cmul(z1, X00);
        const c32 Y00 = { c2, 0.f }, Y01 = { 0.f, -s2 };
        const c32 U00 = { Y00.r*A00.r - Y00.i*A00.i + Y01.r*A10.r - Y01.i*A10.i,
                          Y00.r*A00.i + Y00.i*A00.r + Y01.r*A10.i + Y01.i*A10.r };
        const c32 U01 = { Y00.r*A01.r - Y00.i*A01.i + Y01.r*A11.r - Y01.i*A11.i,
                          Y00.r*A01.i + Y00.i*A01.r + Y01.r*A11.i + Y01.i*A11.r };
        const c32 U10 = { Y01.r*A00.r - Y01.i*A00.i + Y00.r*A10.r - Y00.i*A10.i,
                          Y01.r*A00.i + Y01.i*A00.r + Y00.r*A10.i + Y00.i*A10.r };
        const c32 U11 = { Y01.r*A01.r - Y01.i*A01.i + Y00.r*A11.r - Y00.i*A11.i,
                          Y01.r*A01.i + Y01.i*A01.r + Y00.r*A11.i + Y00.i*A11.r };
        const c32 V00 = { U00.r*M00.r - U00.i*M00.i + U01.r*M10.r - U01.i*M10.i,
                          U00.r*M00.i + U00.i*M00.r + U01.r*M10.i + U01.i*M10.r };
        const c32 V01 = { U00.r*M01.r - U00.i*M01.i + U01.r*M11.r - U01.i*M11.i,
                          U00.r*M01.i + U00.i*M01.r + U01.r*M11.i + U01.i*M11.r };
        const c32 V10 = { U10.r*M00.r - U10.i*M00.i + U11.r*M10.r - U11.i*M10.i,
                          U10.r*M00.i + U10.i*M00.r + U11.r*M10.i + U11.i*M10.r };
        const c32 V11 = { U10.r*M01.r - U10.i*M01.i + U11.r*M11.r - U11.i*M11.i,
                          U10.r*M01.i + U10.i*M01.r + U11.r*M11.i + U11.i*M11.r };

        float cb = sqrtf(V00.r*V00.r + V00.i*V00.i);
        float sb = sqrtf(V10.r*V10.r + V10.i*V10.i);
        c32 p0, p1, q1;
        const float eps = 1e-6f;
        if (sb <= eps) {            // near-diagonal
            const float icb = 1.f / cb;
            p0 = { V00.r*icb, V00.i*icb };
            p1 = { V11.r*icb, V11.i*icb };
            q1 = { 1.f, 0.f };
            cb = 1.f; sb = 0.f;
        } else if (cb <= eps) {     // near-antidiagonal
            const float isb = 1.f / sb;
            p1 = { V10.r*isb, V10.i*isb };
            p0 = { -V01.r*isb, -V01.i*isb };
            q1 = { 1.f, 0.f };
            cb = 0.f; sb = 1.f;
        } else {
            const float icb = 1.f / cb, isb = 1.f / sb;
            p0 = { V00.r*icb, V00.i*icb };
            p1 = { V10.r*isb, V10.i*isb };
            const c32 t = { V11.r*p1.r + V11.i*p1.i, V11.i*p1.r - V11.r*p1.i }; // V11*conj(p1)
            q1 = { t.r*icb, t.i*icb };
        }
        Vs[tid * 2]     = make_float4(cb, sb, p0.r, p0.i);
        Vs[tid * 2 + 1] = make_float4(p1.r, p1.i, q1.r, q1.i);
    }
    __syncthreads();

    // ---- boundary diag tables (layers K=1,2): B_K = P(K) * Q(K+1) o gamma^-1 ----
    if (tid < 64) {
        const int bK = (tid >> 5) + 1;
        const int sg = (tid >> 4) & 1;
        const int j  = tid & 15;
        c32 acc = { 1.f, 0.f };
        #pragma unroll
        for (int m = 3; m >= 0; --m) {
            const int Q = 11 - m;
            const float4 s0 = Vs[(bK*NQ+Q)*2];
            const float4 s1 = Vs[(bK*NQ+Q)*2+1];
            const float4 n1 = Vs[((bK+1)*NQ+Q)*2+1];
            const c32 pf = ((j >> m) & 1) ? c32{ s1.x, s1.y } : c32{ s0.z, s0.w };
            acc = cmul(acc, pf);
            if (sg ^ (__popc(j >> m) & 1)) acc = cmul(acc, c32{ n1.z, n1.w });
        }
        TbS[bK-1][sg][j] = make_float2(acc.r, acc.i);
    } else if (tid < 96) {
        const int idx = tid - 64;
        const int bK = (idx >> 4) + 1;
        const int h  = idx & 15;
        c32 acc = { 1.f, 0.f };
        #pragma unroll
        for (int Q = 0; Q < 4; ++Q) {
            const float4 s0 = Vs[(bK*NQ+Q)*2];
            const float4 s1 = Vs[(bK*NQ+Q)*2+1];
            const float4 n1 = Vs[((bK+1)*NQ+Q)*2+1];
            const c32 pf = ((h >> (3-Q)) & 1) ? c32{ s1.x, s1.y } : c32{ s0.z, s0.w };
            acc = cmul(acc, pf);
            if (__popc(h >> (3-Q)) & 1) acc = cmul(acc, c32{ n1.z, n1.w });
        }
        CHiS[bK-1][h] = make_float2(acc.r, acc.i);
    } else if (tid < 160) {
        const int idx = tid - 96;
        const int bK = (idx >> 5) + 1;
        const int sh = (idx >> 4) & 1;
        const int lo = idx & 15;
        c32 acc = { 1.f, 0.f };
        #pragma unroll
        for (int Q = 4; Q < 8; ++Q) {
            const float4 s0 = Vs[(bK*NQ+Q)*2];
            const float4 s1 = Vs[(bK*NQ+Q)*2+1];
            const float4 n1 = Vs[((bK+1)*NQ+Q)*2+1];
            const c32 pf = ((lo >> (7-Q)) & 1) ? c32{ s1.x, s1.y } : c32{ s0.z, s0.w };
            acc = cmul(acc, pf);
            if (sh ^ (__popc(lo >> (7-Q)) & 1)) acc = cmul(acc, c32{ n1.z, n1.w });
        }
        CLoS[bK-1][sh][lo] = make_float2(acc.r, acc.i);
    }

    // ---- layer 0: tensor product (col-0 factors) with Q(1) folded in ----
    {
        const int sg0 = __popc(tid) & 1;
        c32 C = { 1.f, 0.f };
        #pragma unroll
        for (int q = 0; q < 8; ++q) {
            const float4 s0 = Vs[q*2];
            const float4 s1 = Vs[q*2+1];
            const bool bit = (tid >> (7 - q)) & 1;
            const c32 e = bit ? c32{ s1.x * s0.y, s1.y * s0.y }    // p1*sb
                             : c32{ s0.z * s0.x, s0.w * s0.x };    // p0*cb
            C = cmul(C, e);
            const float4 n1 = Vs[(NQ+q)*2+1];
            if (__popc(tid >> (7 - q)) & 1) C = cmul(C, c32{ n1.z, n1.w });
        }
        c32 pf0[4], pf1[4], qv[4];
        #pragma unroll
        for (int m = 0; m < 4; ++m) {
            const int Q = 11 - m;
            const float4 s0 = Vs[Q*2];
            const float4 s1 = Vs[Q*2+1];
            const float4 n1 = Vs[(NQ+Q)*2+1];
            pf0[m] = { s0.z * s0.x, s0.w * s0.x };
            pf1[m] = { s1.x * s0.y, s1.y * s0.y };
            qv[m]  = { n1.z, n1.w };
        }
        c32 T[16];
        diagTree(T, C, pf0, pf1, qv, sg0);
        const int beta = Cm(tid << 4);
        #pragma unroll
        for (int m = 0; m < 8; ++m)
            a4[(beta ^ (2 * m)) >> 1] =
                make_float4(T[2*m].r, T[2*m].i, T[2*m+1].r, T[2*m+1].i);
    }
    __syncthreads();

    // ---- layers 1..3: RY passes + boundary diag at pass 2 ----
    const int Lo = tid & 15, Hh = tid >> 4;

    #define RUN_LAYER(K)                                                            \
    {                                                                               \
        /* pass 0: qubits 0-3 (t bits 11-8) */                                      \
        {                                                                           \
            const float4 g0 = Vs[(K*NQ+0)*2], g1 = Vs[(K*NQ+1)*2];                  \
            const float4 g2 = Vs[(K*NQ+2)*2], g3 = Vs[(K*NQ+3)*2];                  \
            const int beta = Cm(G(tid, K));                                         \
            c32 v[16];                                                              \
            _Pragma("unroll")                                                       \
            for (int j = 0; j < 16; ++j) {                                          \
                const float2 t = amp[beta ^ Cm(G(j << 8, K))];                      \
                v[j] = { t.x, t.y };                                                \
            }                                                                       \
            applyRY<3>(v, g0.x, g0.y); applyRY<2>(v, g1.x, g1.y);                   \
            applyRY<1>(v, g2.x, g2.y); applyRY<0>(v, g3.x, g3.y);                   \
            _Pragma("unroll")                                                       \
            for (int j = 0; j < 16; ++j)                                            \
                amp[beta ^ Cm(G(j << 8, K))] = make_float2(v[j].r, v[j].i);         \
            __syncthreads();                                                        \
        }                                                                           \
        /* pass 1: qubits 4-7 (t bits 7-4) */                                       \
        {                                                                           \
            const float4 g0 = Vs[(K*NQ+4)*2], g1 = Vs[(K*NQ+5)*2];                  \
            const float4 g2 = Vs[(K*NQ+6)*2], g3 = Vs[(K*NQ+7)*2];                  \
            const int beta = Cm(G((Hh << 8) | Lo, K));                              \
            c32 v[16];                                                              \
            _Pragma("unroll")                                                       \
            for (int j = 0; j < 16; ++j) {                                          \
                const float2 t = amp[beta ^ Cm(G(j << 4, K))];                      \
                v[j] = { t.x, t.y };                                                \
            }                                                                       \
            applyRY<3>(v, g0.x, g0.y); applyRY<2>(v, g1.x, g1.y);                   \
            applyRY<1>(v, g2.x, g2.y); applyRY<0>(v, g3.x, g3.y);                   \
            _Pragma("unroll")                                                       \
            for (int j = 0; j < 16; ++j)                                            \
                amp[beta ^ Cm(G(j << 4, K))] = make_float2(v[j].r, v[j].i);         \
            __syncthreads();                                                        \
        }                                                                           \
        /* pass 2: qubits 8-11 (t bits 3-0), b128; boundary diag before write */    \
        {                                                                           \
            const float4 g0 = Vs[(K*NQ+8)*2],  g1 = Vs[(K*NQ+9)*2];                 \
            const float4 g2 = Vs[(K*NQ+10)*2], g3 = Vs[(K*NQ+11)*2];                \
            const int beta = Cm(G((Hh << 8) | (Lo << 4), K));                       \
            c32 v[16];                                                              \
            _Pragma("unroll")                                                       \
            for (int m = 0; m < 8; ++m) {                                           \
                const int gg = Cm(G(2 * m, K));                                     \
                const float4 F = a4[(beta ^ (gg & ~1)) >> 1];                       \
                const c32 flo = { F.x, F.y }, fhi = { F.z, F.w };                   \
                if (gg & 1) { v[2*m+1] = flo; v[2*m] = fhi; }                       \
                else        { v[2*m] = flo;   v[2*m+1] = fhi; }                     \
            }                                                                       \
            applyRY<3>(v, g0.x, g0.y); applyRY<2>(v, g1.x, g1.y);                   \
            applyRY<1>(v, g2.x, g2.y); applyRY<0>(v, g3.x, g3.y);                   \
            if constexpr (K < 3) {                                                  \
                const int sgm = __popc(tid) & 1;                                    \
                const int sgh = __popc(tid >> 4) & 1;                               \
                const float2 ch = CHiS[K-1][Hh];                                    \
                const float2 cl = CLoS[K-1][sgh][Lo];                               \
                const c32 CT = cmul(c32{ch.x,ch.y}, c32{cl.x,cl.y});                \
                _Pragma("unroll")                                                   \
                for (int j = 0; j < 16; ++j) {                                      \
                    const float2 tb = TbS[K-1][sgm][j];                             \
                    v[j] = cmul(v[j], cmul(CT, c32{tb.x, tb.y}));                   \
                }                                                                   \
            }                                                                       \
            _Pragma("unroll")                                                       \
            for (int m = 0; m < 8; ++m) {                                           \
                const int gg = Cm(G(2 * m, K));                                     \
                float4 F;                                                           \
                if (gg & 1) F = make_float4(v[2*m+1].r, v[2*m+1].i, v[2*m].r,   v[2*m].i); \
                else        F = make_float4(v[2*m].r,   v[2*m].i,   v[2*m+1].r, v[2*m+1].i); \
                a4[(beta ^ (gg & ~1)) >> 1] = F;                                    \
            }                                                                       \
            __syncthreads();                                                        \
        }                                                                           \
    }

    RUN_LAYER(1)
    RUN_LAYER(2)
    RUN_LAYER(3)
    #undef RUN_LAYER

    // ---- readout: weight = parity(MASKE & e); P(3) dropped (pure phase) ----
    float acc = 0.f;
    #pragma unroll
    for (int it = 0; it < 8; ++it) {
        const int pe = (it << 9) | (tid << 1);
        const float4 F = a4[pe >> 1];
        const float m0 = fmaf(F.x, F.x, F.y * F.y);
        const float m1 = fmaf(F.z, F.z, F.w * F.w);
        acc += (__popc(pe & MASKE) & 1) ? -m0 : m0;
        acc += (__popc((pe | 1) & MASKE) & 1) ? -m1 : m1;
    }
    #pragma unroll
    for (int off = 32; off > 0; off >>= 1) acc += __shfl_down(acc, off, 64);
    if ((tid & 63) == 0) red[tid >> 6] = acc;
    __syncthreads();
    if (tid == 0) out[b] = red[0] + red[1] + red[2] + red[3];
}

} // namespace

extern "C" void kernel_launch(void* const* d_in, const int* in_sizes, int n_in,
                              void* d_out, int out_size, void* d_ws, size_t ws_size,
                              hipStream_t stream) {
    const float* x      = (const float*)d_in[0];
    const float* thetas = (const float*)d_in[1];
    float* out          = (float*)d_out;
    const int batch = in_sizes[0];
    qcirc_kernel<<<batch, THREADS, 0, stream>>>(x, thetas, out);
}